// Round 5
// baseline (343.125 us; speedup 1.0000x reference)
//
#include <hip/hip_runtime.h>

typedef unsigned short ushort_t;
typedef _Float16 half8 __attribute__((ext_vector_type(8)));
typedef short short8 __attribute__((ext_vector_type(8)));
typedef float floatx4 __attribute__((ext_vector_type(4)));

#define NCC 65536
#define NPP 1024
#define DD 256
#define NCHUNK 64
#define VROW 40                   // padded vT tile row (80B: 16B-aligned, even spans)
#define VTILE_B (256 * VROW * 2)  // 20480 B per 32-candidate vT tile
#define CLIPL 72.134752f          // 50 * log2(e)

static __device__ __forceinline__ ushort_t f2h_bits(float x) {
  _Float16 h = (_Float16)x;
  return __builtin_bit_cast(ushort_t, h);
}
static __device__ __forceinline__ ushort_t f2bf_bits(float x) {
  unsigned u = __builtin_bit_cast(unsigned, x);
  unsigned r = (u + 0x7FFFu + ((u >> 16) & 1u)) >> 16;
  return (ushort_t)r;
}

// async global->LDS DMA, 16B per lane
static __device__ __forceinline__ void dma16(const void* g, void* l) {
  __builtin_amdgcn_global_load_lds((const __attribute__((address_space(1))) unsigned int*)g,
                                   (__attribute__((address_space(3))) unsigned int*)l, 16, 0, 0);
}

// ---------------------------------------------------------------------------
// K0: Wq/Wk (fp32 [k][n]) -> WF (f16, MFMA B-frag order):
// WF[((g*4+nt)*8 + s)*64 + lane] (8 halves) = W[k=s*32+(lane>>4)*8+j][n=g*64+nt*16+(lane&15)]
// ---------------------------------------------------------------------------
__global__ __launch_bounds__(256) void wt_prep(const float* __restrict__ Wq,
                                               const float* __restrict__ Wk,
                                               ushort_t* __restrict__ WqF,
                                               ushort_t* __restrict__ WkF) {
  __shared__ __align__(16) ushort_t lt[64][72];
  const float* W = blockIdx.y ? Wk : Wq;
  ushort_t* WF = blockIdx.y ? WkF : WqF;
  const int k0 = ((int)blockIdx.x & 3) * 64, n0 = ((int)blockIdx.x >> 2) * 64;
  const int t = threadIdx.x;
#pragma unroll
  for (int i = 0; i < 4; i++) {
    int f = t + 256 * i;
    int k = f >> 4, j = (f & 15) * 4;
    const float4 v = *(const float4*)&W[(size_t)(k0 + k) * DD + n0 + j];
    lt[j + 0][k] = f2h_bits(v.x);
    lt[j + 1][k] = f2h_bits(v.y);
    lt[j + 2][k] = f2h_bits(v.z);
    lt[j + 3][k] = f2h_bits(v.w);
  }
  __syncthreads();
  const int g = n0 >> 6;
#pragma unroll
  for (int i = 0; i < 2; i++) {
    int f = t + 256 * i;  // 512 slots: nt(4) x s_l(2) x lane(64)
    int nt = f >> 7, s_l = (f >> 6) & 1, ln = f & 63;
    int qd = ln >> 4, nn = ln & 15;
    uint4 v = *(const uint4*)&lt[nt * 16 + nn][s_l * 32 + qd * 8];
    size_t slot = ((size_t)(g * 4 + nt) * 8 + (k0 >> 5) + s_l) * 64 + ln;
    *(uint4*)&WF[slot * 8] = v;
  }
}

// ---------------------------------------------------------------------------
// K1: fused GEMM. Q output: row-major f16, PRE-SCALED by log2(e) (incl bias).
// keyf output: MFMA A-frag order kfA[tile(=c/16)][s(8)][lane(64)][8 halves].
// W frags read straight from global (WF layout) — no LDS B panel, no DMA.
// ---------------------------------------------------------------------------
__global__ __launch_bounds__(256) void prep_gemm(
    const float* __restrict__ box_feat, const float* __restrict__ points_feat,
    const float* __restrict__ centers, const float* __restrict__ scales,
    const ushort_t* __restrict__ WqF, const ushort_t* __restrict__ WkF,
    const float* __restrict__ bq, const float* __restrict__ bk,
    ushort_t* __restrict__ q_out, ushort_t* __restrict__ kfA,
    float2* __restrict__ xy) {
  __shared__ __align__(16) ushort_t lds_a[64][264];
  __shared__ __align__(16) ushort_t lds_o[64][72];
  __shared__ float lds_s[64];

  const int t = threadIdx.x;
  const bool isQ = (blockIdx.x >= (NCC / 64));
  const int row0 = isQ ? ((int)blockIdx.x - NCC / 64) * 64 : (int)blockIdx.x * 64;
  const float* In = isQ ? points_feat : box_feat;
  const ushort_t* WF = isQ ? WqF : WkF;
  const float* Bi = isQ ? bq : bk;

  if (t < 64) {
    float s = 1.0f;
    if (!isQ) {
      int c = row0 + t;
      float stride = centers[c * 4 + 3];
      int lvl = (int)(log2f(stride) + 0.5f) - 3;
      lvl = lvl < 0 ? 0 : (lvl > 4 ? 4 : lvl);
      s = scales[lvl];
      float hf = floorf(centers[c * 4 + 2] * 0.5f);
      xy[c] = make_float2(centers[c * 4 + 1] + hf, centers[c * 4 + 0] + hf);
    }
    lds_s[t] = s;
  }
  __syncthreads();

#pragma unroll
  for (int i = 0; i < 16; i++) {
    int f = t + 256 * i;
    int r = f >> 6;
    int c4 = (f & 63) * 4;
    const float4 v = *(const float4*)&In[(size_t)(row0 + r) * DD + c4];
    float s = lds_s[r];
    ushort_t h0 = f2h_bits(v.x * s), h1 = f2h_bits(v.y * s);
    ushort_t h2 = f2h_bits(v.z * s), h3 = f2h_bits(v.w * s);
    *(uint2*)&lds_a[r][c4] =
        make_uint2((unsigned)h0 | ((unsigned)h1 << 16), (unsigned)h2 | ((unsigned)h3 << 16));
  }
  __syncthreads();  // A staged

  const int w = t >> 6, lane = t & 63, qd = lane >> 4, n = lane & 15;

  for (int g = 0; g < 4; ++g) {
    floatx4 acc[4] = {};
#pragma unroll
    for (int s = 0; s < 8; s++) {
      half8 af = __builtin_bit_cast(half8, *(const uint4*)&lds_a[w * 16 + n][s * 32 + qd * 8]);
#pragma unroll
      for (int nt = 0; nt < 4; ++nt) {
        half8 bf = __builtin_bit_cast(
            half8, *(const uint4*)&WF[(((size_t)(g * 4 + nt) * 8 + s) * 64 + lane) * 8]);
        acc[nt] = __builtin_amdgcn_mfma_f32_16x16x32_f16(af, bf, acc[nt], 0, 0, 0);
      }
    }
    __syncthreads();  // lds_o free (prev copyout done)
#pragma unroll
    for (int nt = 0; nt < 4; ++nt) {
      float b = Bi[g * 64 + nt * 16 + n];
#pragma unroll
      for (int r = 0; r < 4; r++) {
        float v = acc[nt][r] + b;
        if (isQ) v *= 1.44269504f;  // pre-scale query by log2(e)
        lds_o[w * 16 + qd * 4 + r][nt * 16 + n] = f2h_bits(v);
      }
    }
    __syncthreads();
    if (isQ) {
      // row-major copyout
#pragma unroll
      for (int i = 0; i < 2; i++) {
        int f = t + 256 * i;
        int r = f >> 3, grp = f & 7;
        *(uint4*)&q_out[(size_t)(row0 + r) * DD + g * 64 + grp * 8] =
            *(const uint4*)&lds_o[r][grp * 8];
      }
    } else {
      // kfA frag copyout: slot = (tile*8 + g*2+s_l)*64 + ln, wave-contiguous 1KB
#pragma unroll
      for (int i = 0; i < 2; i++) {
        int f = t + 256 * i;
        int ct = f >> 7, s_l = (f >> 6) & 1, ln = f & 63;
        int lqd = ln >> 4, lnn = ln & 15;
        uint4 v = *(const uint4*)&lds_o[ct * 16 + lnn][s_l * 32 + lqd * 8];
        size_t slot = ((size_t)((row0 >> 4) + ct) * 8 + g * 2 + s_l) * 64 + ln;
        *(uint4*)&kfA[slot * 8] = v;
      }
    }
  }
}

// ---------------------------------------------------------------------------
// K2: transpose box_feat (fp32 [NC][256]) -> vTb (bf16, blocked+padded VROW=40)
// ---------------------------------------------------------------------------
__global__ __launch_bounds__(256) void transpose_v(const float* __restrict__ box_feat,
                                                   ushort_t* __restrict__ vTb) {
  __shared__ __align__(16) ushort_t lt[64][72];
  const int t = threadIdx.x;
  const int c0 = blockIdx.x * 64, d0 = blockIdx.y * 64;
#pragma unroll
  for (int i = 0; i < 4; i++) {
    int f = t + 256 * i;
    int c = f >> 4;
    int j = (f & 15) * 4;
    const float4 v = *(const float4*)&box_feat[(size_t)(c0 + c) * DD + d0 + j];
    lt[j + 0][c] = f2bf_bits(v.x);
    lt[j + 1][c] = f2bf_bits(v.y);
    lt[j + 2][c] = f2bf_bits(v.z);
    lt[j + 3][c] = f2bf_bits(v.w);
  }
  __syncthreads();
#pragma unroll
  for (int i = 0; i < 2; i++) {
    int f = t + 256 * i;  // 64 d x 8 c-groups
    int d = f >> 3, j = f & 7;
    int tile = (c0 >> 5) + (j >> 2);
    size_t ob = (size_t)tile * (256 * VROW) + (size_t)(d0 + d) * VROW + (j & 3) * 8;
    *(uint4*)&vTb[ob] = *(const uint4*)&lt[d][j * 8];
  }
}

// ---------------------------------------------------------------------------
// K3: fused attention. Block = 4 waves x 32 points; grid (64 chunks, 8 pg).
// kf A-frags: coalesced GLOBAL b128 loads from kfA (no LDS, no barrier dep,
// compiler-pipelined vmcnt). vT + xy: DMA double-buffer, ONE barrier/iter,
// staged right after the barrier -> drains at the NEXT barrier.
// ---------------------------------------------------------------------------
template <bool PART>
__global__ __launch_bounds__(256, 2) void attn_kernel(
    const ushort_t* __restrict__ qf16, const ushort_t* __restrict__ kfA,
    const ushort_t* __restrict__ vTb, const float2* __restrict__ xy,
    const float* __restrict__ boxes, float* __restrict__ acc_out,
    float* __restrict__ den_out) {
  __shared__ __align__(16) ushort_t lds_v[2][256 * VROW];  // 2 x 20KB
  __shared__ __align__(16) ushort_t lds_p[4][32][VROW];    // 10KB
  __shared__ __align__(16) float2 lds_xy[2][32];

  const int t = threadIdx.x;
  const int w = t >> 6, lane = t & 63, qd = lane >> 4, n = lane & 15;
  const int chunk = blockIdx.x;
  const int p0w = blockIdx.y * 128 + w * 32;
  const int cchunk = chunk * 1024;

  half8 qfr[2][8];
  float4 bxv[2];
#pragma unroll
  for (int pt = 0; pt < 2; ++pt) {
    int p = p0w + pt * 16 + n;
#pragma unroll
    for (int s = 0; s < 8; s++)
      qfr[pt][s] =
          __builtin_bit_cast(half8, *(const uint4*)&qf16[(size_t)p * DD + s * 32 + qd * 8]);
    bxv[pt] = *(const float4*)&boxes[p * 4];
  }

  floatx4 macc[2][16] = {};
  float dsum0 = 0.f, dsum1 = 0.f;

  auto stage = [&](int it2, int b) {
    const char* src = (const char*)vTb + ((size_t)(cchunk >> 5) + it2) * VTILE_B;
    char* dst = (char*)lds_v[b];
#pragma unroll
    for (int jj = 0; jj < 5; ++jj) {
      int i = w * 5 + jj;
      dma16(src + i * 1024 + lane * 16, dst + i * 1024 + lane * 16);
    }
    if (w == 0 && lane < 16)
      dma16((const char*)xy + ((size_t)cchunk + it2 * 32) * 8 + lane * 16,
            (char*)lds_xy[b] + lane * 16);
  };

  stage(0, 0);

  for (int it = 0; it < 32; ++it) {
    const int buf = it & 1;
    __syncthreads();                          // drains stage(it)
    if (it + 1 < 32) stage(it + 1, buf ^ 1);  // drains at NEXT barrier

    // QK^T: A-frags from global kfA (coalesced 1KB loads, L2-resident)
    const size_t tbase = (size_t)(cchunk >> 4) + it * 2;
#pragma unroll
    for (int t2 = 0; t2 < 2; ++t2) {
      const ushort_t* kb = kfA + (tbase + t2) * 4096;
      floatx4 a0 = {}, a1 = {};
#pragma unroll
      for (int s = 0; s < 8; s++) {
        half8 af = __builtin_bit_cast(half8, *(const uint4*)&kb[(s * 64 + lane) * 8]);
        a0 = __builtin_amdgcn_mfma_f32_16x16x32_f16(af, qfr[0][s], a0, 0, 0, 0);
        a1 = __builtin_amdgcn_mfma_f32_16x16x32_f16(af, qfr[1][s], a1, 0, 0, 0);
      }
      unsigned pk00 = 0, pk01 = 0, pk10 = 0, pk11 = 0;
#pragma unroll
      for (int r = 0; r < 4; r++) {
        int cl = t2 * 16 + qd * 4 + r;
        float2 pxy = lds_xy[buf][cl];
        {
          float mn = fminf(fminf(pxy.x - bxv[0].x, pxy.y - bxv[0].y),
                           fminf(bxv[0].z - pxy.x, bxv[0].w - pxy.y));
          float simL = fminf(a0[r], CLIPL);
          float e = (mn > 0.f) ? exp2f(simL - CLIPL) : 0.f;
          dsum0 += e;
          unsigned b = (unsigned)f2bf_bits(e);
          if (r == 0) pk00 = b;
          else if (r == 1) pk00 |= b << 16;
          else if (r == 2) pk01 = b;
          else pk01 |= b << 16;
        }
        {
          float mn = fminf(fminf(pxy.x - bxv[1].x, pxy.y - bxv[1].y),
                           fminf(bxv[1].z - pxy.x, bxv[1].w - pxy.y));
          float simL = fminf(a1[r], CLIPL);
          float e = (mn > 0.f) ? exp2f(simL - CLIPL) : 0.f;
          dsum1 += e;
          unsigned b = (unsigned)f2bf_bits(e);
          if (r == 0) pk10 = b;
          else if (r == 1) pk10 |= b << 16;
          else if (r == 2) pk11 = b;
          else pk11 |= b << 16;
        }
      }
      *(uint2*)&lds_p[w][n][t2 * 16 + qd * 4] = make_uint2(pk00, pk01);
      *(uint2*)&lds_p[w][16 + n][t2 * 16 + qd * 4] = make_uint2(pk10, pk11);
    }
    // same-wave LDS RAW on lds_p
    __asm__ volatile("s_waitcnt lgkmcnt(0)" ::: "memory");

    short8 a20 = __builtin_bit_cast(short8, *(const uint4*)&lds_p[w][n][qd * 8]);
    short8 a21 = __builtin_bit_cast(short8, *(const uint4*)&lds_p[w][16 + n][qd * 8]);
#pragma unroll
    for (int dt = 0; dt < 16; ++dt) {
      short8 b2 =
          __builtin_bit_cast(short8, *(const uint4*)&lds_v[buf][(dt * 16 + n) * VROW + qd * 8]);
      macc[0][dt] = __builtin_amdgcn_mfma_f32_16x16x32_bf16(a20, b2, macc[0][dt], 0, 0, 0);
      macc[1][dt] = __builtin_amdgcn_mfma_f32_16x16x32_bf16(a21, b2, macc[1][dt], 0, 0, 0);
    }
  }

  dsum0 += __shfl_xor(dsum0, 16, 64);
  dsum0 += __shfl_xor(dsum0, 32, 64);
  dsum1 += __shfl_xor(dsum1, 16, 64);
  dsum1 += __shfl_xor(dsum1, 32, 64);

  if (PART) {
    if (lane < 16) {
      den_out[(size_t)chunk * NPP + p0w + n] = dsum0;
      den_out[(size_t)chunk * NPP + p0w + 16 + n] = dsum1;
    }
    float* ab = acc_out + (size_t)chunk * NPP * DD;
#pragma unroll
    for (int pt = 0; pt < 2; ++pt)
#pragma unroll
      for (int dt = 0; dt < 16; ++dt)
#pragma unroll
        for (int r = 0; r < 4; r++)
          ab[(size_t)(p0w + pt * 16 + qd * 4 + r) * DD + dt * 16 + n] = macc[pt][dt][r];
  } else {
    if (lane < 16) {
      atomicAdd(&den_out[p0w + n], dsum0);
      atomicAdd(&den_out[p0w + 16 + n], dsum1);
    }
#pragma unroll
    for (int pt = 0; pt < 2; ++pt)
#pragma unroll
      for (int dt = 0; dt < 16; ++dt)
#pragma unroll
        for (int r = 0; r < 4; r++)
          atomicAdd(&acc_out[(size_t)(p0w + pt * 16 + qd * 4 + r) * DD + dt * 16 + n],
                    macc[pt][dt][r]);
  }
}

// ---------------------------------------------------------------------------
// K4a: reduce partials over chunks + finalize (PART path)
// ---------------------------------------------------------------------------
__global__ __launch_bounds__(256) void reduce_finalize(const float* __restrict__ points_feat,
                                                       const float* __restrict__ acc_part,
                                                       const float* __restrict__ den_part,
                                                       float* __restrict__ out) {
  const int p = blockIdx.x, t = threadIdx.x;
  float s = 0.f;
#pragma unroll 4
  for (int c = 0; c < NCHUNK; ++c) s += acc_part[((size_t)c * NPP + p) * DD + t];
  float dn = den_part[(size_t)(t & 63) * NPP + p];
#pragma unroll
  for (int o = 1; o < 64; o <<= 1) dn += __shfl_xor(dn, o, 64);
  float m = (dn > 0.f) ? s / dn : 0.f;
  out[(size_t)p * DD + t] = points_feat[(size_t)p * DD + t] + m;
}

// K4b: atomic-path finalize
__global__ void finalize(const float* __restrict__ points_feat, const float* __restrict__ acc,
                         const float* __restrict__ den, float* __restrict__ out) {
  int p = blockIdx.x, d = threadIdx.x;
  float dn = den[p];
  float m = (dn > 0.f) ? acc[p * DD + d] / dn : 0.f;
  out[p * DD + d] = points_feat[p * DD + d] + m;
}

extern "C" void kernel_launch(void* const* d_in, const int* in_sizes, int n_in, void* d_out,
                              int out_size, void* d_ws, size_t ws_size, hipStream_t stream) {
  const float* points_feat = (const float*)d_in[0];
  const float* box_feat = (const float*)d_in[1];
  const float* centers = (const float*)d_in[2];
  const float* boxes = (const float*)d_in[3];
  const float* Wq = (const float*)d_in[4];
  const float* bq = (const float*)d_in[5];
  const float* Wk = (const float*)d_in[6];
  const float* bk = (const float*)d_in[7];
  const float* scales = (const float*)d_in[8];

  char* p = (char*)d_ws;
  ushort_t* ws_q = (ushort_t*)p;    p += (size_t)NPP * DD * 2;
  ushort_t* ws_kfA = (ushort_t*)p;  p += (size_t)NCC * DD * 2;
  ushort_t* ws_vTb = (ushort_t*)p;  p += (size_t)(NCC / 32) * VTILE_B;
  float2* ws_xy = (float2*)p;       p += (size_t)NCC * 8;
  ushort_t* ws_wqF = (ushort_t*)p;  p += (size_t)DD * DD * 2;
  ushort_t* ws_wkF = (ushort_t*)p;  p += (size_t)DD * DD * 2;
  float* ws_den = (float*)p;        p += (size_t)NCHUNK * NPP * 4;
  float* ws_acc = (float*)p;
  size_t need_part = (size_t)(p - (char*)d_ws) + (size_t)NCHUNK * NPP * DD * 4;
  const bool part = ws_size >= need_part;

  wt_prep<<<dim3(16, 2), 256, 0, stream>>>(Wq, Wk, ws_wqF, ws_wkF);
  prep_gemm<<<NCC / 64 + NPP / 64, 256, 0, stream>>>(box_feat, points_feat, centers, scales,
                                                     ws_wqF, ws_wkF, bq, bk, ws_q, ws_kfA, ws_xy);
  transpose_v<<<dim3(NCC / 64, DD / 64), 256, 0, stream>>>(box_feat, ws_vTb);
  if (part) {
    attn_kernel<true><<<dim3(NCHUNK, 8), 256, 0, stream>>>(ws_q, ws_kfA, ws_vTb, ws_xy, boxes,
                                                           ws_acc, ws_den);
    reduce_finalize<<<NPP, 256, 0, stream>>>(points_feat, ws_acc, ws_den, (float*)d_out);
  } else {
    hipMemsetAsync(ws_den, 0, ((size_t)NPP * DD + NPP) * sizeof(float), stream);
    float* acc1 = ws_den + NPP;
    attn_kernel<false><<<dim3(NCHUNK, 8), 256, 0, stream>>>(ws_q, ws_kfA, ws_vTb, ws_xy, boxes,
                                                            acc1, ws_den);
    finalize<<<NPP, DD, 0, stream>>>(points_feat, acc1, ws_den, (float*)d_out);
  }
}

// Round 6
// 299.305 us; speedup vs baseline: 1.1464x; 1.1464x over previous
//
#include <hip/hip_runtime.h>

typedef unsigned short ushort_t;
typedef _Float16 half8 __attribute__((ext_vector_type(8)));
typedef short short8 __attribute__((ext_vector_type(8)));
typedef float floatx4 __attribute__((ext_vector_type(4)));

#define NCC 65536
#define NPP 1024
#define DD 256
#define NCHUNK 64
#define VROW 36                   // padded vT/P row in halves (72B)
#define VTILE_B (256 * VROW * 2)  // 18432 B per 32-candidate vT tile
#define L2E 1.44269504f
#define CLIPL 72.134752f          // 50 * log2(e)

static __device__ __forceinline__ ushort_t f2h_bits(float x) {
  _Float16 h = (_Float16)x;
  return __builtin_bit_cast(ushort_t, h);
}
static __device__ __forceinline__ ushort_t f2bf_bits(float x) {
  unsigned u = __builtin_bit_cast(unsigned, x);
  unsigned r = (u + 0x7FFFu + ((u >> 16) & 1u)) >> 16;
  return (ushort_t)r;
}
static __device__ __forceinline__ float bf2f(ushort_t b) {
  unsigned u = ((unsigned)b) << 16;
  return __builtin_bit_cast(float, u);
}
// load 8 consecutive fp32, convert to f16 frag
static __device__ __forceinline__ half8 cvt8(const float* p) {
  float4 a = *(const float4*)p, b = *(const float4*)(p + 4);
  half8 h;
  h[0] = (_Float16)a.x; h[1] = (_Float16)a.y; h[2] = (_Float16)a.z; h[3] = (_Float16)a.w;
  h[4] = (_Float16)b.x; h[5] = (_Float16)b.y; h[6] = (_Float16)b.z; h[7] = (_Float16)b.w;
  return h;
}
// async global->LDS DMA, 16B per lane
static __device__ __forceinline__ void dma16(const void* g, void* l) {
  __builtin_amdgcn_global_load_lds((const __attribute__((address_space(1))) unsigned int*)g,
                                   (__attribute__((address_space(3))) unsigned int*)l, 16, 0, 0);
}
static __device__ __forceinline__ short8 mk_s8(uint2 lo, uint2 hi) {
  uint4 u;
  u.x = lo.x; u.y = lo.y; u.z = hi.x; u.w = hi.y;
  return __builtin_bit_cast(short8, u);
}

// ---------------------------------------------------------------------------
// K_A1: Mk = Wk @ Wq^T (f16, row-major [d][e]); block 16: tu = Wk@bq,
// tv = Wq@bk, s0 = bk.bq
// ---------------------------------------------------------------------------
__global__ __launch_bounds__(256) void mk_prep(const float* __restrict__ Wq,
                                               const float* __restrict__ Wk,
                                               const float* __restrict__ bq,
                                               const float* __restrict__ bk,
                                               ushort_t* __restrict__ Mk, float* __restrict__ tu,
                                               float* __restrict__ tv, float* __restrict__ s0v) {
  const int t = threadIdx.x;
  if (blockIdx.x == 16) {
    float su = 0.f, sv = 0.f;
    for (int j = 0; j < DD; j += 4) {
      float4 a = *(const float4*)&Wk[(size_t)t * DD + j];
      float4 b = *(const float4*)&bq[j];
      su += a.x * b.x + a.y * b.y + a.z * b.z + a.w * b.w;
      float4 c = *(const float4*)&Wq[(size_t)t * DD + j];
      float4 d = *(const float4*)&bk[j];
      sv += c.x * d.x + c.y * d.y + c.z * d.z + c.w * d.w;
    }
    tu[t] = su;
    tv[t] = sv;
    __shared__ float red[256];
    red[t] = bk[t] * bq[t];
    __syncthreads();
    for (int o = 128; o; o >>= 1) {
      if (t < o) red[t] += red[t + o];
      __syncthreads();
    }
    if (t == 0) s0v[0] = red[0];
    return;
  }
  const int m0 = ((int)blockIdx.x & 3) * 64, e0 = ((int)blockIdx.x >> 2) * 64;
  const int w = t >> 6, lane = t & 63, qd = lane >> 4, n = lane & 15;
  floatx4 acc[4] = {};
#pragma unroll
  for (int s = 0; s < 8; s++) {
    half8 af = cvt8(&Wk[(size_t)(m0 + w * 16 + n) * DD + s * 32 + qd * 8]);
#pragma unroll
    for (int nt = 0; nt < 4; ++nt) {
      half8 bf = cvt8(&Wq[(size_t)(e0 + nt * 16 + n) * DD + s * 32 + qd * 8]);
      acc[nt] = __builtin_amdgcn_mfma_f32_16x16x32_f16(af, bf, acc[nt], 0, 0, 0);
    }
  }
#pragma unroll
  for (int nt = 0; nt < 4; ++nt)
#pragma unroll
    for (int r = 0; r < 4; r++)
      Mk[(size_t)(m0 + w * 16 + qd * 4 + r) * DD + e0 + nt * 16 + n] = f2h_bits(acc[nt][r]);
}

// ---------------------------------------------------------------------------
// K_A2: Gt = pf @ Mk^T (f16 row-major [p][d]); gamma[p] = L2E*(pf_p.tv + s0) - CLIPL
// ---------------------------------------------------------------------------
__global__ __launch_bounds__(256) void gt_prep(const float* __restrict__ pf,
                                               const ushort_t* __restrict__ Mk,
                                               const float* __restrict__ tv,
                                               const float* __restrict__ s0v,
                                               ushort_t* __restrict__ Gt,
                                               float* __restrict__ gamma) {
  const int t = threadIdx.x, p0 = (int)blockIdx.x * 64;
  const int w = t >> 6, lane = t & 63, qd = lane >> 4, n = lane & 15;
  floatx4 acc[16] = {};
#pragma unroll
  for (int s = 0; s < 8; s++) {
    half8 af = cvt8(&pf[(size_t)(p0 + w * 16 + n) * DD + s * 32 + qd * 8]);
#pragma unroll
    for (int nt = 0; nt < 16; ++nt) {
      half8 bf = __builtin_bit_cast(half8,
                                    *(const uint4*)&Mk[(size_t)(nt * 16 + n) * DD + s * 32 + qd * 8]);
      acc[nt] = __builtin_amdgcn_mfma_f32_16x16x32_f16(af, bf, acc[nt], 0, 0, 0);
    }
  }
#pragma unroll
  for (int nt = 0; nt < 16; ++nt)
#pragma unroll
    for (int r = 0; r < 4; r++)
      Gt[(size_t)(p0 + w * 16 + qd * 4 + r) * DD + nt * 16 + n] = f2h_bits(acc[nt][r]);
  if (t < 64) {
    float s = s0v[0];
    for (int j = 0; j < DD; j += 4) {
      float4 a = *(const float4*)&pf[(size_t)(p0 + t) * DD + j];
      float4 b = *(const float4*)&tv[j];
      s += a.x * b.x + a.y * b.y + a.z * b.z + a.w * b.w;
    }
    gamma[p0 + t] = s * L2E - CLIPL;
  }
}

// ---------------------------------------------------------------------------
// K_B: single pass over box_feat (32 candidates/block):
//  - bfR: f16 rows, 16B-group XOR swizzle (group ^= c&7) for bank-balanced LDS
//  - vTb: bf16 transposed tiles [tile][d][VROW=36]
//  - meta[c] = (alpha, beta, xs, ys)  [alpha=w*L2E, beta=w*(bf_c.tu)*L2E]
// ---------------------------------------------------------------------------
__global__ __launch_bounds__(256) void bt_prep(const float* __restrict__ bf,
                                               const float* __restrict__ centers,
                                               const float* __restrict__ scales,
                                               const float* __restrict__ tu,
                                               ushort_t* __restrict__ bfR,
                                               ushort_t* __restrict__ vTb,
                                               float4* __restrict__ meta) {
  __shared__ float tu_s[256];
  __shared__ __align__(16) ushort_t lt[256][40];
  const int t = threadIdx.x, c0 = (int)blockIdx.x * 32;
  tu_s[t] = tu[t];
  __syncthreads();
  const int c = t >> 3, sub = t & 7;
  float du = 0.f;
#pragma unroll
  for (int i = 0; i < 8; i++) {
    int f4 = sub + 8 * i;
    int d0 = f4 * 4;
    float4 v = *(const float4*)&bf[(size_t)(c0 + c) * DD + d0];
    du += v.x * tu_s[d0] + v.y * tu_s[d0 + 1] + v.z * tu_s[d0 + 2] + v.w * tu_s[d0 + 3];
    // f16 row-major with XOR swizzle (16B groups)
    int l = f4 >> 1;
    int u = (l & ~7) | ((l & 7) ^ (c & 7));
    ushort_t h0 = f2h_bits(v.x), h1 = f2h_bits(v.y), h2 = f2h_bits(v.z), h3 = f2h_bits(v.w);
    *(uint2*)&bfR[(size_t)(c0 + c) * DD + u * 8 + (d0 & 7)] =
        make_uint2((unsigned)h0 | ((unsigned)h1 << 16), (unsigned)h2 | ((unsigned)h3 << 16));
    // transposed bf16 staging
    lt[d0 + 0][c] = f2bf_bits(v.x);
    lt[d0 + 1][c] = f2bf_bits(v.y);
    lt[d0 + 2][c] = f2bf_bits(v.z);
    lt[d0 + 3][c] = f2bf_bits(v.w);
  }
  du += __shfl_xor(du, 1, 64);
  du += __shfl_xor(du, 2, 64);
  du += __shfl_xor(du, 4, 64);
  if (sub == 0) {
    const float4 ce = *(const float4*)&centers[(size_t)(c0 + c) * 4];  // y,x,stride,stride
    int lvl = (int)(log2f(ce.w) + 0.5f) - 3;
    lvl = lvl < 0 ? 0 : (lvl > 4 ? 4 : lvl);
    float wsc = scales[lvl];
    float hf = floorf(ce.z * 0.5f);
    meta[c0 + c] = make_float4(wsc * L2E, wsc * du * L2E, ce.y + hf, ce.x + hf);
  }
  __syncthreads();
  // copyout vT tile: thread t = row d, 36 halves = 9 x uint2
  char* dst = (char*)vTb + (size_t)blockIdx.x * VTILE_B + (size_t)t * (VROW * 2);
  const char* src = (const char*)&lt[t][0];
#pragma unroll
  for (int i = 0; i < 9; i++) *(uint2*)(dst + i * 8) = *(const uint2*)(src + i * 8);
}

// ---------------------------------------------------------------------------
// K3: fused attention (round-4 structure). Block = 4 waves x 32 points;
// grid (64 chunks, 8 pg). Per iter: barrier -> DMA-stage next (bfR tile 16KB +
// vT tile 18KB + meta 0.5KB) -> QK f16 MFMA from lds_k -> mask/exp (alpha*raw
// + beta + gamma, clip, exp2) -> P via per-wave LDS -> PV bf16 MFMA.
// PART: bf16 per-chunk partials via plain stores; else fp32 atomics.
// ---------------------------------------------------------------------------
template <bool PART>
__global__ __launch_bounds__(256, 2) void attn_kernel(
    const ushort_t* __restrict__ Gt, const float* __restrict__ gamma,
    const ushort_t* __restrict__ bfR, const ushort_t* __restrict__ vTb,
    const float4* __restrict__ meta, const float* __restrict__ boxes,
    void* __restrict__ acc_out, float* __restrict__ den_out) {
  __shared__ __align__(16) ushort_t lds_k[2][32 * 256];    // 32KB
  __shared__ __align__(16) ushort_t lds_v[2][256 * VROW];  // 36KB
  __shared__ __align__(16) ushort_t lds_p[4][32][VROW];    // 9KB
  __shared__ __align__(16) float4 lds_m[2][32];            // 1KB

  const int t = threadIdx.x;
  const int w = t >> 6, lane = t & 63, qd = lane >> 4, n = lane & 15;
  const int chunk = blockIdx.x;
  const int p0w = blockIdx.y * 128 + w * 32;
  const int cchunk = chunk * 1024;
  const int sw16 = (n & 7) * 16;

  half8 gfr[2][8];
  float4 bxv[2];
  float gam[2];
#pragma unroll
  for (int pt = 0; pt < 2; ++pt) {
    int p = p0w + pt * 16 + n;
#pragma unroll
    for (int s = 0; s < 8; s++)
      gfr[pt][s] = __builtin_bit_cast(half8, *(const uint4*)&Gt[(size_t)p * DD + s * 32 + qd * 8]);
    bxv[pt] = *(const float4*)&boxes[(size_t)p * 4];
    gam[pt] = gamma[p];
  }

  floatx4 macc[2][16] = {};
  float dsum0 = 0.f, dsum1 = 0.f;

  auto stage = [&](int it2, int b) {
    const char* ks = (const char*)bfR + (size_t)(cchunk + it2 * 32) * 512;
    char* kd = (char*)lds_k[b];
#pragma unroll
    for (int j = 0; j < 4; ++j) {
      int i = w * 4 + j;
      dma16(ks + i * 1024 + lane * 16, kd + i * 1024 + lane * 16);
    }
    const char* vs = (const char*)vTb + ((size_t)(cchunk >> 5) + it2) * VTILE_B;
    char* vd = (char*)lds_v[b];
#pragma unroll
    for (int j = 0; j < 4; ++j) {
      int i = j * 4 + w;
      dma16(vs + i * 1024 + lane * 16, vd + i * 1024 + lane * 16);
    }
    if (w < 2) {
      int i = 16 + w;
      dma16(vs + i * 1024 + lane * 16, vd + i * 1024 + lane * 16);
    }
    if (w == 0 && lane < 32)
      dma16((const char*)meta + (size_t)(cchunk + it2 * 32) * 16 + lane * 16,
            (char*)lds_m[b] + lane * 16);
  };

  stage(0, 0);

  for (int it = 0; it < 32; ++it) {
    const int buf = it & 1;
    __syncthreads();                          // drains stage(it)
    if (it + 1 < 32) stage(it + 1, buf ^ 1);  // drains at NEXT barrier

#pragma unroll
    for (int t2 = 0; t2 < 2; ++t2) {
      const char* krow = (const char*)lds_k[buf] + (t2 * 16 + n) * 512;
      floatx4 a0 = {}, a1 = {};
#pragma unroll
      for (int s = 0; s < 8; s++) {
        half8 af = __builtin_bit_cast(half8, *(const uint4*)(krow + ((s * 64 + qd * 16) ^ sw16)));
        a0 = __builtin_amdgcn_mfma_f32_16x16x32_f16(af, gfr[0][s], a0, 0, 0, 0);
        a1 = __builtin_amdgcn_mfma_f32_16x16x32_f16(af, gfr[1][s], a1, 0, 0, 0);
      }
      unsigned pk00 = 0, pk01 = 0, pk10 = 0, pk11 = 0;
#pragma unroll
      for (int r = 0; r < 4; r++) {
        int cl = t2 * 16 + qd * 4 + r;
        float4 mt = lds_m[buf][cl];  // alpha, beta, xs, ys
        {
          float mn = fminf(fminf(mt.z - bxv[0].x, mt.w - bxv[0].y),
                           fminf(bxv[0].z - mt.z, bxv[0].w - mt.w));
          float targ = fmaf(mt.x, a0[r], mt.y) + gam[0];
          float e = (mn > 0.f) ? exp2f(fminf(targ, 0.f)) : 0.f;
          dsum0 += e;
          unsigned b = (unsigned)f2bf_bits(e);
          if (r == 0) pk00 = b;
          else if (r == 1) pk00 |= b << 16;
          else if (r == 2) pk01 = b;
          else pk01 |= b << 16;
        }
        {
          float mn = fminf(fminf(mt.z - bxv[1].x, mt.w - bxv[1].y),
                           fminf(bxv[1].z - mt.z, bxv[1].w - mt.w));
          float targ = fmaf(mt.x, a1[r], mt.y) + gam[1];
          float e = (mn > 0.f) ? exp2f(fminf(targ, 0.f)) : 0.f;
          dsum1 += e;
          unsigned b = (unsigned)f2bf_bits(e);
          if (r == 0) pk10 = b;
          else if (r == 1) pk10 |= b << 16;
          else if (r == 2) pk11 = b;
          else pk11 |= b << 16;
        }
      }
      *(uint2*)&lds_p[w][n][t2 * 16 + qd * 4] = make_uint2(pk00, pk01);
      *(uint2*)&lds_p[w][16 + n][t2 * 16 + qd * 4] = make_uint2(pk10, pk11);
    }
    // same-wave LDS RAW on lds_p (DS ops only; DMA uses vmcnt)
    __asm__ volatile("s_waitcnt lgkmcnt(0)" ::: "memory");

    const char* pr0 = (const char*)&lds_p[w][n][0];
    const char* pr1 = (const char*)&lds_p[w][16 + n][0];
    short8 a20 = mk_s8(*(const uint2*)(pr0 + qd * 16), *(const uint2*)(pr0 + qd * 16 + 8));
    short8 a21 = mk_s8(*(const uint2*)(pr1 + qd * 16), *(const uint2*)(pr1 + qd * 16 + 8));
#pragma unroll
    for (int dt = 0; dt < 16; ++dt) {
      const char* vrow = (const char*)lds_v[buf] + (dt * 16 + n) * (VROW * 2);
      short8 b2 = mk_s8(*(const uint2*)(vrow + qd * 16), *(const uint2*)(vrow + qd * 16 + 8));
      macc[0][dt] = __builtin_amdgcn_mfma_f32_16x16x32_bf16(a20, b2, macc[0][dt], 0, 0, 0);
      macc[1][dt] = __builtin_amdgcn_mfma_f32_16x16x32_bf16(a21, b2, macc[1][dt], 0, 0, 0);
    }
  }

  dsum0 += __shfl_xor(dsum0, 16, 64);
  dsum0 += __shfl_xor(dsum0, 32, 64);
  dsum1 += __shfl_xor(dsum1, 16, 64);
  dsum1 += __shfl_xor(dsum1, 32, 64);

  if (PART) {
    if (lane < 16) {
      den_out[(size_t)chunk * NPP + p0w + n] = dsum0;
      den_out[(size_t)chunk * NPP + p0w + 16 + n] = dsum1;
    }
    ushort_t* ab = (ushort_t*)acc_out + (size_t)chunk * NPP * DD;
#pragma unroll
    for (int pt = 0; pt < 2; ++pt)
#pragma unroll
      for (int dt = 0; dt < 16; ++dt)
#pragma unroll
        for (int r = 0; r < 4; r++)
          ab[(size_t)(p0w + pt * 16 + qd * 4 + r) * DD + dt * 16 + n] = f2bf_bits(macc[pt][dt][r]);
  } else {
    if (lane < 16) {
      atomicAdd(&den_out[p0w + n], dsum0);
      atomicAdd(&den_out[p0w + 16 + n], dsum1);
    }
    float* ab = (float*)acc_out;
#pragma unroll
    for (int pt = 0; pt < 2; ++pt)
#pragma unroll
      for (int dt = 0; dt < 16; ++dt)
#pragma unroll
        for (int r = 0; r < 4; r++)
          atomicAdd(&ab[(size_t)(p0w + pt * 16 + qd * 4 + r) * DD + dt * 16 + n],
                    macc[pt][dt][r]);
  }
}

// ---------------------------------------------------------------------------
// K4a: reduce bf16 partials over chunks + finalize (PART path)
// ---------------------------------------------------------------------------
__global__ __launch_bounds__(256) void reduce_finalize(const float* __restrict__ points_feat,
                                                       const ushort_t* __restrict__ acc_part,
                                                       const float* __restrict__ den_part,
                                                       float* __restrict__ out) {
  const int p = blockIdx.x, t = threadIdx.x;
  float s = 0.f;
#pragma unroll 4
  for (int c = 0; c < NCHUNK; ++c) s += bf2f(acc_part[((size_t)c * NPP + p) * DD + t]);
  float dn = den_part[(size_t)(t & 63) * NPP + p];
#pragma unroll
  for (int o = 1; o < 64; o <<= 1) dn += __shfl_xor(dn, o, 64);
  float m = (dn > 0.f) ? s / dn : 0.f;
  out[(size_t)p * DD + t] = points_feat[(size_t)p * DD + t] + m;
}

// K4b: atomic-path finalize
__global__ void finalize(const float* __restrict__ points_feat, const float* __restrict__ acc,
                         const float* __restrict__ den, float* __restrict__ out) {
  int p = blockIdx.x, d = threadIdx.x;
  float dn = den[p];
  float m = (dn > 0.f) ? acc[p * DD + d] / dn : 0.f;
  out[p * DD + d] = points_feat[p * DD + d] + m;
}

extern "C" void kernel_launch(void* const* d_in, const int* in_sizes, int n_in, void* d_out,
                              int out_size, void* d_ws, size_t ws_size, hipStream_t stream) {
  const float* points_feat = (const float*)d_in[0];
  const float* box_feat = (const float*)d_in[1];
  const float* centers = (const float*)d_in[2];
  const float* boxes = (const float*)d_in[3];
  const float* Wq = (const float*)d_in[4];
  const float* bq = (const float*)d_in[5];
  const float* Wk = (const float*)d_in[6];
  const float* bk = (const float*)d_in[7];
  const float* scales = (const float*)d_in[8];

  char* p = (char*)d_ws;
  ushort_t* ws_accP = (ushort_t*)p;  p += (size_t)NCHUNK * NPP * DD * 2;  // 33.55MB (bf16)
  float* ws_den = (float*)p;         p += (size_t)NCHUNK * NPP * 4;       // 0.26MB
  ushort_t* ws_bfR = (ushort_t*)p;   p += (size_t)NCC * DD * 2;           // 33.55MB
  ushort_t* ws_vTb = (ushort_t*)p;   p += (size_t)(NCC / 32) * VTILE_B;   // 37.75MB
  ushort_t* ws_Gt = (ushort_t*)p;    p += (size_t)NPP * DD * 2;           // 0.52MB
  float4* ws_meta = (float4*)p;      p += (size_t)NCC * 16;               // 1.05MB
  float* ws_gamma = (float*)p;       p += (size_t)NPP * 4;                // 4KB
  size_t need_part = (size_t)(p - (char*)d_ws);

  if (ws_size >= need_part) {
    // aux buffers (dead once attn starts) carved from the partials region
    ushort_t* ws_Mk = ws_accP;                        // 128KB
    float* ws_tu = (float*)(ws_Mk + (size_t)DD * DD); // 1KB
    float* ws_tv = ws_tu + DD;                        // 1KB
    float* ws_s0 = ws_tv + DD;                        // 4B

    mk_prep<<<17, 256, 0, stream>>>(Wq, Wk, bq, bk, ws_Mk, ws_tu, ws_tv, ws_s0);
    gt_prep<<<16, 256, 0, stream>>>(points_feat, ws_Mk, ws_tv, ws_s0, ws_Gt, ws_gamma);
    bt_prep<<<NCC / 32, 256, 0, stream>>>(box_feat, centers, scales, ws_tu, ws_bfR, ws_vTb,
                                          ws_meta);
    attn_kernel<true><<<dim3(NCHUNK, 8), 256, 0, stream>>>(ws_Gt, ws_gamma, ws_bfR, ws_vTb,
                                                           ws_meta, boxes, ws_accP, ws_den);
    reduce_finalize<<<NPP, 256, 0, stream>>>(points_feat, ws_accP, ws_den, (float*)d_out);
  } else {
    // compact fallback: fp32 atomic accumulation
    char* q = (char*)d_ws;
    ushort_t* f_bfR = (ushort_t*)q;  q += (size_t)NCC * DD * 2;
    ushort_t* f_vTb = (ushort_t*)q;  q += (size_t)(NCC / 32) * VTILE_B;
    ushort_t* f_Gt = (ushort_t*)q;   q += (size_t)NPP * DD * 2;
    float4* f_meta = (float4*)q;     q += (size_t)NCC * 16;
    float* f_gamma = (float*)q;      q += (size_t)NPP * 4;
    float* f_den = (float*)q;        q += (size_t)NPP * 4;
    float* f_acc = (float*)q;        q += (size_t)NPP * DD * 4;
    ushort_t* f_Mk = (ushort_t*)f_acc;  // carved: consumed before memset/attn
    float* f_tu = (float*)(f_Mk + (size_t)DD * DD);
    float* f_tv = f_tu + DD;
    float* f_s0 = f_tv + DD;

    mk_prep<<<17, 256, 0, stream>>>(Wq, Wk, bq, bk, f_Mk, f_tu, f_tv, f_s0);
    gt_prep<<<16, 256, 0, stream>>>(points_feat, f_Mk, f_tv, f_s0, f_Gt, f_gamma);
    bt_prep<<<NCC / 32, 256, 0, stream>>>(box_feat, centers, scales, f_tu, f_bfR, f_vTb, f_meta);
    hipMemsetAsync(f_den, 0, ((size_t)NPP * DD + NPP) * sizeof(float), stream);
    attn_kernel<false><<<dim3(NCHUNK, 8), 256, 0, stream>>>(f_Gt, f_gamma, f_bfR, f_vTb, f_meta,
                                                            boxes, f_acc, f_den);
    finalize<<<NPP, DD, 0, stream>>>(points_feat, f_acc, f_den, (float*)d_out);
  }
}